// Round 2
// baseline (2837.422 us; speedup 1.0000x reference)
//
#include <hip/hip_runtime.h>
#include <cstddef>

#define BB   16384
#define TT_  100
#define FF   64
#define K4   20
#define NOUT 3
#define TC   4            // timesteps per chunk
#define NCH  (TT_ / TC)   // 25 chunks

__device__ __forceinline__ float sigf(float x) {
    // 1/(1+e^-x); rcp ~1ulp, fine vs 5.9e-4 threshold
    return __builtin_amdgcn_rcpf(1.0f + __expf(-x));
}
__device__ __forceinline__ float tanhf_fast(float x) {
    // tanh(x) = 1 - 2/(e^{2x}+1); safe at +/-inf
    return 1.0f - 2.0f * __builtin_amdgcn_rcpf(__expf(2.0f * x) + 1.0f);
}
template <int IMM>
__device__ __forceinline__ float swz(float v) {
    return __int_as_float(__builtin_amdgcn_ds_swizzle(__float_as_int(v), IMM));
}

// ---------------------------------------------------------------------------
// Fused: x-projection + 3-layer LSTM recurrence + head, one wave per 8 batch
// elements.  Per 4-t chunk: lanes act as (b,tq,fh) computing x@W1 with
// wave-uniform W1 LDS broadcasts; z goes through a small LDS buffer to the
// recurrence mapping (b,u) where lane u owns unit u's i/f/g/o; h all-gather
// via static ds_swizzle (group-of-8 broadcast).  No __syncthreads (1 wave).
// ---------------------------------------------------------------------------
__global__ __launch_bounds__(64, 2) void fused_lstm_kernel(
    const float* __restrict__ x,    // [B][T][F]
    const float* __restrict__ W1, const float* __restrict__ U1, const float* __restrict__ b1,
    const float* __restrict__ W2, const float* __restrict__ U2, const float* __restrict__ b2,
    const float* __restrict__ W3, const float* __restrict__ U3, const float* __restrict__ b3,
    const float* __restrict__ Wd, const float* __restrict__ bd,
    float* __restrict__ out)        // [B][NOUT]
{
    __shared__ float sWT[K4][FF];        // W1 transposed: sWT[k][f]
    __shared__ float zbuf[TC][K4][9];    // +pad breaks tq/k bank aliasing

    const int lane = threadIdx.x;        // 0..63
    const int g    = lane >> 3;          // batch-in-block 0..7
    const int u    = lane & 7;           // unit lane (5 active + 3 dup)
    const int ue   = (u < 5) ? u : 4;
    const int tq   = (lane >> 1) & 3;    // proj-phase timestep 0..3
    const int fh   = lane & 1;           // proj-phase f-half
    const int b    = blockIdx.x * 8 + g;

    // ---- issue chunk-0 x loads first (overlap HBM latency with setup)
    const float* xrow = x + ((size_t)b * TT_ + tq) * FF + fh * 32;
    float4 xa[8];
#pragma unroll
    for (int fc = 0; fc < 8; ++fc) xa[fc] = ((const float4*)xrow)[fc];

    // ---- stage W1^T into LDS (1280 floats, once)
#pragma unroll
    for (int w = 0; w < 20; ++w) {
        int i = w * 64 + lane;
        sWT[i % K4][i / K4] = W1[i];
    }

    // ---- per-lane recurrent weight columns (k = j*5 + ue)
    float u1w[4][5], w2w[4][5], u2w[4][5], w3w[4][5], u3w[4][5];
    float bb1[4], bb2[4], bb3[4];
#pragma unroll
    for (int j = 0; j < 4; ++j) {
        const int k = j * 5 + ue;
#pragma unroll
        for (int d = 0; d < 5; ++d) {
            u1w[j][d] = U1[d * K4 + k];
            w2w[j][d] = W2[d * K4 + k];
            u2w[j][d] = U2[d * K4 + k];
            w3w[j][d] = W3[d * K4 + k];
            u3w[j][d] = U3[d * K4 + k];
        }
        bb1[j] = b1[k];
        bb2[j] = b2[k];
        bb3[j] = b3[k];
    }
    const int uo = (u < NOUT) ? u : 0;
    float wdw[5];
    const float bdw = bd[uo];
#pragma unroll
    for (int d = 0; d < 5; ++d) wdw[d] = Wd[d * NOUT + uo];

    float h1[5] = {0,0,0,0,0}, h2[5] = {0,0,0,0,0}, h3[5] = {0,0,0,0,0};
    float c1 = 0.f, c2 = 0.f, c3 = 0.f;

    for (int c = 0; c < NCH; ++c) {
        // ================= projection phase: lanes = (g, tq, fh) ==========
        float pk[K4];
#pragma unroll
        for (int k = 0; k < K4; ++k) pk[k] = 0.f;
#pragma unroll
        for (int fc = 0; fc < 8; ++fc) {
            const float4 xv = xa[fc];
            const int f0 = fh * 32 + fc * 4;
#pragma unroll
            for (int k = 0; k < K4; ++k) {          // k wave-uniform -> LDS broadcast
                const float4 wv = *(const float4*)&sWT[k][f0];
                pk[k] = fmaf(xv.x, wv.x,
                        fmaf(xv.y, wv.y,
                        fmaf(xv.z, wv.z,
                        fmaf(xv.w, wv.w, pk[k]))));
            }
        }

        // ---- prefetch next chunk's x into xa (lands during rec phase)
        if (c + 1 < NCH) {
            const float* xn = xrow + (size_t)TC * FF;
#pragma unroll
            for (int fc = 0; fc < 8; ++fc) xa[fc] = ((const float4*)xn)[fc];
            xrow = xn;
        }

        // ---- combine f-halves (xor-1 butterfly) and write z to LDS
#pragma unroll
        for (int k = 0; k < K4; ++k) pk[k] += swz<0x041F>(pk[k]);
#pragma unroll
        for (int j = 0; j < 10; ++j) {
            const float v = fh ? pk[10 + j] : pk[j];   // static reg indices
            zbuf[tq][fh * 10 + j][g] = v;
        }

        // ================= recurrence phase: lanes = (g, u) ===============
#pragma unroll
        for (int s = 0; s < TC; ++s) {
            float z[4];
            // ---- layer 1: z = xz + b1 + h1@U1
#pragma unroll
            for (int j = 0; j < 4; ++j) {
                float acc = zbuf[s][j * 5 + ue][g] + bb1[j];
#pragma unroll
                for (int d = 0; d < 5; ++d) acc = fmaf(h1[d], u1w[j][d], acc);
                z[j] = acc;
            }
            {
                const float iv = sigf(z[0]), fv = sigf(z[1]);
                const float gv = tanhf_fast(z[2]), ov = sigf(z[3]);
                c1 = fmaf(fv, c1, iv * gv);
                const float ho = ov * tanhf_fast(c1);
                h1[0] = swz<0x018>(ho); h1[1] = swz<0x038>(ho);
                h1[2] = swz<0x058>(ho); h1[3] = swz<0x078>(ho);
                h1[4] = swz<0x098>(ho);
            }
            // ---- layer 2
#pragma unroll
            for (int j = 0; j < 4; ++j) {
                float acc = bb2[j];
#pragma unroll
                for (int d = 0; d < 5; ++d) acc = fmaf(h1[d], w2w[j][d], acc);
#pragma unroll
                for (int d = 0; d < 5; ++d) acc = fmaf(h2[d], u2w[j][d], acc);
                z[j] = acc;
            }
            {
                const float iv = sigf(z[0]), fv = sigf(z[1]);
                const float gv = tanhf_fast(z[2]), ov = sigf(z[3]);
                c2 = fmaf(fv, c2, iv * gv);
                const float ho = ov * tanhf_fast(c2);
                h2[0] = swz<0x018>(ho); h2[1] = swz<0x038>(ho);
                h2[2] = swz<0x058>(ho); h2[3] = swz<0x078>(ho);
                h2[4] = swz<0x098>(ho);
            }
            // ---- layer 3
#pragma unroll
            for (int j = 0; j < 4; ++j) {
                float acc = bb3[j];
#pragma unroll
                for (int d = 0; d < 5; ++d) acc = fmaf(h2[d], w3w[j][d], acc);
#pragma unroll
                for (int d = 0; d < 5; ++d) acc = fmaf(h3[d], u3w[j][d], acc);
                z[j] = acc;
            }
            {
                const float iv = sigf(z[0]), fv = sigf(z[1]);
                const float gv = tanhf_fast(z[2]), ov = sigf(z[3]);
                c3 = fmaf(fv, c3, iv * gv);
                const float ho = ov * tanhf_fast(c3);
                h3[0] = swz<0x018>(ho); h3[1] = swz<0x038>(ho);
                h3[2] = swz<0x058>(ho); h3[3] = swz<0x078>(ho);
                h3[4] = swz<0x098>(ho);
            }
        }
    }

    // ---- output head: out[b][u] for u < 3
    if (u < NOUT) {
        float s = bdw;
#pragma unroll
        for (int d = 0; d < 5; ++d) s = fmaf(h3[d], wdw[d], s);
        out[b * NOUT + u] = s;
    }
}

extern "C" void kernel_launch(void* const* d_in, const int* in_sizes, int n_in,
                              void* d_out, int out_size, void* d_ws, size_t ws_size,
                              hipStream_t stream) {
    const float* x   = (const float*)d_in[0];
    const float* W1  = (const float*)d_in[1];
    const float* U1  = (const float*)d_in[2];
    const float* b1  = (const float*)d_in[3];
    const float* W2  = (const float*)d_in[4];
    const float* U2  = (const float*)d_in[5];
    const float* b2  = (const float*)d_in[6];
    const float* W3  = (const float*)d_in[7];
    const float* U3  = (const float*)d_in[8];
    const float* b3  = (const float*)d_in[9];
    const float* Wd  = (const float*)d_in[10];
    const float* bdp = (const float*)d_in[11];
    float* out = (float*)d_out;

    fused_lstm_kernel<<<BB / 8, 64, 0, stream>>>(
        x, W1, U1, b1, W2, U2, b2, W3, U3, b3, Wd, bdp, out);
}

// Round 3
// 626.896 us; speedup vs baseline: 4.5261x; 4.5261x over previous
//
#include <hip/hip_runtime.h>
#include <cstddef>

#define BB   16384
#define TT_  100
#define FF   64
#define K4   20
#define NOUT 3

__device__ __forceinline__ float sigf(float x) {
    // 1/(1+e^-x); rcp ~1ulp, fine vs 5.9e-4 threshold
    return __builtin_amdgcn_rcpf(1.0f + __expf(-x));
}
__device__ __forceinline__ float tanhf_fast(float x) {
    // tanh(x) = 1 - 2/(e^{2x}+1); safe at +/-inf
    return 1.0f - 2.0f * __builtin_amdgcn_rcpf(__expf(2.0f * x) + 1.0f);
}
template <int IMM>
__device__ __forceinline__ float swz(float v) {
    return __int_as_float(__builtin_amdgcn_ds_swizzle(__float_as_int(v), IMM));
}

// Recurrence over NT timesteps (state passed by ref, fully inlined/unrolled).
template <int NT>
__device__ __forceinline__ void rec_steps(
    float (&zbuf)[8][K4][9], int g, int ue,
    const float (&u1w)[4][5], const float (&w2w)[4][5], const float (&u2w)[4][5],
    const float (&w3w)[4][5], const float (&u3w)[4][5],
    const float (&bb1)[4], const float (&bb2)[4], const float (&bb3)[4],
    float (&h1)[5], float (&h2)[5], float (&h3)[5],
    float &c1, float &c2, float &c3)
{
#pragma unroll
    for (int s = 0; s < NT; ++s) {
        float z[4];
        // ---- layer 1: z = xW1 + b1 + h1@U1
#pragma unroll
        for (int j = 0; j < 4; ++j) {
            float acc = zbuf[s][j * 5 + ue][g] + bb1[j];
#pragma unroll
            for (int d = 0; d < 5; ++d) acc = fmaf(h1[d], u1w[j][d], acc);
            z[j] = acc;
        }
        {
            const float iv = sigf(z[0]), fv = sigf(z[1]);
            const float gv = tanhf_fast(z[2]), ov = sigf(z[3]);
            c1 = fmaf(fv, c1, iv * gv);
            const float ho = ov * tanhf_fast(c1);
            h1[0] = swz<0x018>(ho); h1[1] = swz<0x038>(ho);
            h1[2] = swz<0x058>(ho); h1[3] = swz<0x078>(ho);
            h1[4] = swz<0x098>(ho);
        }
        // ---- layer 2
#pragma unroll
        for (int j = 0; j < 4; ++j) {
            float acc = bb2[j];
#pragma unroll
            for (int d = 0; d < 5; ++d) acc = fmaf(h1[d], w2w[j][d], acc);
#pragma unroll
            for (int d = 0; d < 5; ++d) acc = fmaf(h2[d], u2w[j][d], acc);
            z[j] = acc;
        }
        {
            const float iv = sigf(z[0]), fv = sigf(z[1]);
            const float gv = tanhf_fast(z[2]), ov = sigf(z[3]);
            c2 = fmaf(fv, c2, iv * gv);
            const float ho = ov * tanhf_fast(c2);
            h2[0] = swz<0x018>(ho); h2[1] = swz<0x038>(ho);
            h2[2] = swz<0x058>(ho); h2[3] = swz<0x078>(ho);
            h2[4] = swz<0x098>(ho);
        }
        // ---- layer 3
#pragma unroll
        for (int j = 0; j < 4; ++j) {
            float acc = bb3[j];
#pragma unroll
            for (int d = 0; d < 5; ++d) acc = fmaf(h2[d], w3w[j][d], acc);
#pragma unroll
            for (int d = 0; d < 5; ++d) acc = fmaf(h3[d], u3w[j][d], acc);
            z[j] = acc;
        }
        {
            const float iv = sigf(z[0]), fv = sigf(z[1]);
            const float gv = tanhf_fast(z[2]), ov = sigf(z[3]);
            c3 = fmaf(fv, c3, iv * gv);
            const float ho = ov * tanhf_fast(c3);
            h3[0] = swz<0x018>(ho); h3[1] = swz<0x038>(ho);
            h3[2] = swz<0x058>(ho); h3[3] = swz<0x078>(ho);
            h3[4] = swz<0x098>(ho);
        }
    }
}

// ---------------------------------------------------------------------------
// Fused x-proj + 3-layer LSTM + head.  One wave per 8 batch elements.
// Chunk = 8 timesteps: proj lanes (g,tq,fh) each own 2 rows (t0+tq, t0+4+tq),
// k-outer loop reads each W1 float4 once (2-addr LDS broadcast, free) and
// feeds 8 FMAs.  Recurrence lanes (g,u): lane u owns unit u's i/f/g/o;
// h broadcast via static ds_swizzle.  waves_per_eu(2,2) pins VGPR cap at 256
// so the ~220 live regs do NOT spill (round-2 failure mode: 128-cap spills,
// 2.7 GB scratch writes).
// ---------------------------------------------------------------------------
__global__ __launch_bounds__(64) __attribute__((amdgpu_waves_per_eu(2, 2)))
void fused_lstm_kernel(
    const float* __restrict__ x,
    const float* __restrict__ W1, const float* __restrict__ U1, const float* __restrict__ b1,
    const float* __restrict__ W2, const float* __restrict__ U2, const float* __restrict__ b2,
    const float* __restrict__ W3, const float* __restrict__ U3, const float* __restrict__ b3,
    const float* __restrict__ Wd, const float* __restrict__ bd,
    float* __restrict__ out)
{
    __shared__ float sWT[K4][FF];      // W1^T
    __shared__ float zbuf[8][K4][9];   // [t-in-chunk][k][g+pad]

    const int lane = threadIdx.x;
    const int g    = lane >> 3;        // batch-in-block 0..7
    const int u    = lane & 7;         // unit lane (5 active + 3 dup)
    const int ue   = (u < 5) ? u : 4;
    const int tq   = (lane >> 1) & 3;  // proj timestep-quarter
    const int fh   = lane & 1;         // proj f-half
    const int b    = blockIdx.x * 8 + g;

    // ---- chunk-0 x loads first (hide HBM latency behind setup)
    const float* xp0 = x + ((size_t)b * TT_ + tq) * FF + fh * 32;
    const float* xp1 = xp0 + 4 * FF;
    float4 xa0[8], xa1[8];
#pragma unroll
    for (int fc = 0; fc < 8; ++fc) xa0[fc] = ((const float4*)xp0)[fc];
#pragma unroll
    for (int fc = 0; fc < 8; ++fc) xa1[fc] = ((const float4*)xp1)[fc];

    // ---- stage W1^T into LDS
#pragma unroll
    for (int w = 0; w < 20; ++w) {
        int i = w * 64 + lane;
        sWT[i % K4][i / K4] = W1[i];
    }

    // ---- per-lane recurrent weight columns (k = j*5 + ue)
    float u1w[4][5], w2w[4][5], u2w[4][5], w3w[4][5], u3w[4][5];
    float bb1[4], bb2[4], bb3[4];
#pragma unroll
    for (int j = 0; j < 4; ++j) {
        const int k = j * 5 + ue;
#pragma unroll
        for (int d = 0; d < 5; ++d) {
            u1w[j][d] = U1[d * K4 + k];
            w2w[j][d] = W2[d * K4 + k];
            u2w[j][d] = U2[d * K4 + k];
            w3w[j][d] = W3[d * K4 + k];
            u3w[j][d] = U3[d * K4 + k];
        }
        bb1[j] = b1[k];
        bb2[j] = b2[k];
        bb3[j] = b3[k];
    }
    const int uo = (u < NOUT) ? u : 0;
    float wdw[5];
    const float bdw = bd[uo];
#pragma unroll
    for (int d = 0; d < 5; ++d) wdw[d] = Wd[d * NOUT + uo];

    float h1[5] = {0,0,0,0,0}, h2[5] = {0,0,0,0,0}, h3[5] = {0,0,0,0,0};
    float c1 = 0.f, c2 = 0.f, c3 = 0.f;

    const int t1 = tq + (fh << 2);     // zbuf slot this lane writes

    for (int c = 0; c < 13; ++c) {     // 12 full chunks of 8t + tail of 4t
        // ============ projection: k-outer, each W float4 read once ========
#pragma unroll 4
        for (int k = 0; k < K4; ++k) {
            float a0 = 0.f, a1 = 0.f;
#pragma unroll
            for (int fc = 0; fc < 8; ++fc) {
                const float4 wv = *(const float4*)&sWT[k][fh * 32 + fc * 4];
                const float4 x0 = xa0[fc];
                const float4 x1 = xa1[fc];
                a0 = fmaf(x0.x, wv.x, fmaf(x0.y, wv.y, fmaf(x0.z, wv.z, fmaf(x0.w, wv.w, a0))));
                a1 = fmaf(x1.x, wv.x, fmaf(x1.y, wv.y, fmaf(x1.z, wv.z, fmaf(x1.w, wv.w, a1))));
            }
            a0 += swz<0x041F>(a0);     // combine f-halves (xor-1 butterfly)
            a1 += swz<0x041F>(a1);
            zbuf[t1][k][g] = fh ? a1 : a0;
        }

        // ---- prefetch next chunk (lands during recurrence)
        if (c < 12) {
            xp0 += 8 * FF;
            xp1 = (c == 11) ? xp0 : (xp1 + 8 * FF);  // tail: clamp (rows 100+ OOB)
#pragma unroll
            for (int fc = 0; fc < 8; ++fc) xa0[fc] = ((const float4*)xp0)[fc];
#pragma unroll
            for (int fc = 0; fc < 8; ++fc) xa1[fc] = ((const float4*)xp1)[fc];
        }

        // ============ recurrence ==========================================
        if (c < 12) {
            rec_steps<8>(zbuf, g, ue, u1w, w2w, u2w, w3w, u3w,
                         bb1, bb2, bb3, h1, h2, h3, c1, c2, c3);
        } else {
            rec_steps<4>(zbuf, g, ue, u1w, w2w, u2w, w3w, u3w,
                         bb1, bb2, bb3, h1, h2, h3, c1, c2, c3);
        }
    }

    // ---- output head
    if (u < NOUT) {
        float s = bdw;
#pragma unroll
        for (int d = 0; d < 5; ++d) s = fmaf(h3[d], wdw[d], s);
        out[b * NOUT + u] = s;
    }
}

extern "C" void kernel_launch(void* const* d_in, const int* in_sizes, int n_in,
                              void* d_out, int out_size, void* d_ws, size_t ws_size,
                              hipStream_t stream) {
    const float* x   = (const float*)d_in[0];
    const float* W1  = (const float*)d_in[1];
    const float* U1  = (const float*)d_in[2];
    const float* b1  = (const float*)d_in[3];
    const float* W2  = (const float*)d_in[4];
    const float* U2  = (const float*)d_in[5];
    const float* b2  = (const float*)d_in[6];
    const float* W3  = (const float*)d_in[7];
    const float* U3  = (const float*)d_in[8];
    const float* b3  = (const float*)d_in[9];
    const float* Wd  = (const float*)d_in[10];
    const float* bdp = (const float*)d_in[11];
    float* out = (float*)d_out;

    fused_lstm_kernel<<<BB / 8, 64, 0, stream>>>(
        x, W1, U1, b1, W2, U2, b2, W3, U3, b3, Wd, bdp, out);
}